// Round 5
// baseline (427.297 us; speedup 1.0000x reference)
//
#include <hip/hip_runtime.h>
#include <hip/hip_bf16.h>
#include <math.h>

// Problem constants
#define BB 32
#define TT 2048
#define DD 64
#define NCHUNK 4
#define TCH (TT / NCHUNK)           // t-range per block (512)
#define LOG2E 1.4426950408889634f
#define C2    0.7213475204444817f   // log2(e)/2
#define LN2   0.6931471805599453f

typedef __attribute__((ext_vector_type(8))) _Float16 h16x8;  // 8 f16 (4 VGPRs)
typedef __attribute__((ext_vector_type(4))) float    f32x4;  // MFMA C/D frag

// ws layout (bytes)
#define OFF_M    0u                         // float[32*64]          = 8 KB
#define OFF_HI   8192u                      // f16[32*2048*64]       = 8 MB
#define OFF_LO   (8192u + 8388608u)         // f16[32*2048*64]       = 8 MB
#define OFF_PART (8192u + 16777216u)        // float2[NCHUNK*65536]  = 2 MB
// total ~18.8 MB

__device__ __forceinline__ float h2f(unsigned short u) {
    _Float16 h; __builtin_memcpy(&h, &u, 2); return (float)h;
}
__device__ __forceinline__ unsigned short f2h(float f) {
    _Float16 h = (_Float16)f; unsigned short u; __builtin_memcpy(&u, &h, 2); return u;
}
__device__ __forceinline__ float fexp2(float x) {
    float r; asm("v_exp_f32 %0, %1" : "=v"(r) : "v"(x)); return r;
}
__device__ __forceinline__ float flog2(float x) {
    float r; asm("v_log_f32 %0, %1" : "=v"(r) : "v"(x)); return r;
}

// ---------- kernel 1: fused L2-normalize -> f16 hi/lo split + M[b,d] sum ----------
// grid BB*16 = 512 blocks, 256 thr (4 waves). Block: 128 rows of batch b.
// Wave processes 4 rows at a time via float4 (lane: sub=l>>4 row, d4=l&15 quad).
__global__ void k_prep(const float* __restrict__ emb,
                       unsigned short* __restrict__ hi, unsigned short* __restrict__ lo,
                       float* __restrict__ M) {
    const int b    = blockIdx.x >> 4;
    const int R0   = (blockIdx.x & 15) * 128;
    const int w    = threadIdx.x >> 6;
    const int l    = threadIdx.x & 63;
    const int sub  = l >> 4;
    const int d4   = l & 15;

    float macc[4] = {0.f, 0.f, 0.f, 0.f};

    #pragma unroll
    for (int it = 0; it < 8; ++it) {
        int row = R0 + w * 32 + it * 4 + sub;
        size_t base = ((size_t)(b * TT + row)) * DD + d4 * 4;
        float4 v = *(const float4*)(emb + base);
        float ss = v.x * v.x + v.y * v.y + v.z * v.z + v.w * v.w;
        #pragma unroll
        for (int off = 1; off < 16; off <<= 1) ss += __shfl_xor(ss, off);
        float inv = 1.0f / fmaxf(sqrtf(ss), 1e-8f);
        float n0 = v.x * inv, n1 = v.y * inv, n2 = v.z * inv, n3 = v.w * inv;
        ushort4 hv, lv;
        hv.x = f2h(n0); lv.x = f2h(n0 - h2f(hv.x));
        hv.y = f2h(n1); lv.y = f2h(n1 - h2f(hv.y));
        hv.z = f2h(n2); lv.z = f2h(n2 - h2f(hv.z));
        hv.w = f2h(n3); lv.w = f2h(n3 - h2f(hv.w));
        *(ushort4*)(hi + base) = hv;
        *(ushort4*)(lo + base) = lv;
        macc[0] += n0; macc[1] += n1; macc[2] += n2; macc[3] += n3;
    }
    // sum over the 4 sub-rows groups (lanes xor 16, 32)
    #pragma unroll
    for (int j = 0; j < 4; ++j) {
        macc[j] += __shfl_xor(macc[j], 16);
        macc[j] += __shfl_xor(macc[j], 32);
    }
    if (l < 16) {
        #pragma unroll
        for (int j = 0; j < 4; ++j)
            atomicAdd(&M[b * DD + d4 * 4 + j], macc[j]);
    }
}

// ---------- kernel 2: MFMA GEMM (f16 hi*hi + lo*hi) + fused KL epilogue ----------
// grid (32, 32): x = px*NCHUNK + chunk. 512 thr = 8 waves; wave owns 32 p-rows.
__launch_bounds__(512, 8)
__global__ void k_main(const unsigned short* __restrict__ hi,
                       const unsigned short* __restrict__ lo,
                       const float* __restrict__ tic,
                       const float* __restrict__ M,
                       float2* __restrict__ part) {
    __shared__ unsigned short Bh[64 * 64];   // 8 KB, swizzled [t][d]
    __shared__ float ticrow[TT];             // 8 KB
    __shared__ float Msh[DD];
    __shared__ float wred[8];

    const int b     = blockIdx.y;
    const int px    = blockIdx.x >> 2;
    const int chunk = blockIdx.x & 3;
    const int p0    = px * 256;
    const int tbase = chunk * TCH;
    const int tid   = threadIdx.x;
    const int w     = tid >> 6;
    const int l     = tid & 63;
    const int lr    = l & 15;
    const int lg    = l >> 4;

    // --- tic row: load + per-b max + normalize in LDS ---
    float m = -1e30f;
    for (int t = tid; t < TT; t += 512) {
        float v = tic[b * TT + t];
        ticrow[t] = v;
        m = fmaxf(m, v);
    }
    #pragma unroll
    for (int off = 32; off; off >>= 1) m = fmaxf(m, __shfl_xor(m, off));
    if (l == 0) wred[w] = m;
    if (tid < DD) Msh[tid] = M[b * DD + tid];
    __syncthreads();
    float mm = wred[0];
    #pragma unroll
    for (int i = 1; i < 8; ++i) mm = fmaxf(mm, wred[i]);
    float inv = 1.0f / mm;
    for (int t = tid; t < TT; t += 512) ticrow[t] *= inv;  // own entries only

    // --- persistent A fragments: rows p0 + w*32 + mi*16 + lr, k = ks*32 + lg*8 ---
    h16x8 Ah[2][2], Al[2][2];
    #pragma unroll
    for (int mi = 0; mi < 2; ++mi)
        #pragma unroll
        for (int ks = 0; ks < 2; ++ks) {
            size_t off = ((size_t)(b * TT + p0 + w * 32 + mi * 16 + lr)) * DD + ks * 32 + lg * 8;
            Ah[mi][ks] = *(const h16x8*)(hi + off);
            Al[mi][ks] = *(const h16x8*)(lo + off);
        }

    __syncthreads();   // normalized ticrow + Msh visible

    // --- sinv: dot(ne_p, M) from A-frags ---
    float mv[16];
    *(float4*)&mv[0]  = *(const float4*)&Msh[lg * 8];
    *(float4*)&mv[4]  = *(const float4*)&Msh[lg * 8 + 4];
    *(float4*)&mv[8]  = *(const float4*)&Msh[32 + lg * 8];
    *(float4*)&mv[12] = *(const float4*)&Msh[32 + lg * 8 + 4];
    float dotv[2];
    #pragma unroll
    for (int mi = 0; mi < 2; ++mi) {
        float s = 0.f;
        #pragma unroll
        for (int ks = 0; ks < 2; ++ks)
            #pragma unroll
            for (int e = 0; e < 8; ++e) {
                float av = (float)Ah[mi][ks][e] + (float)Al[mi][ks][e];
                s = fmaf(av, mv[ks * 8 + e], s);
            }
        s += __shfl_xor(s, 16);
        s += __shfl_xor(s, 32);
        dotv[mi] = s;
    }

    // --- per-row constants (C rows mi*16 + lg*4 + rr) ---
    float a_[2][4], b_[2][4], si_[2][4], sip_[2][4], SP[2][4], KA[2][4];
    #pragma unroll
    for (int mi = 0; mi < 2; ++mi)
        #pragma unroll
        for (int rr = 0; rr < 4; ++rr) {
            float dv = __shfl(dotv[mi], lg * 4 + rr);
            float si = 1.0f / (dv + (float)TT);
            si_[mi][rr]  = si;
            sip_[mi][rr] = si + 1e-6f;
            float tp = ticrow[p0 + w * 32 + mi * 16 + lg * 4 + rr];
            a_[mi][rr] = -C2 * tp * tp;
            b_[mi][rr] = LOG2E * tp;
            SP[mi][rr] = 0.f; KA[mi][rr] = 0.f;
        }

    // --- t-loop over this chunk ---
    for (int tile = 0; tile < TCH / 64; ++tile) {
        const int t0 = tbase + tile * 64;
        __syncthreads();
        {   // stage B-tile (64 t x 64 d, hi only), XOR-swizzled 16B chunks
            int r  = tid >> 3;
            int kc = tid & 7;
            size_t g = ((size_t)(b * TT + t0 + r)) * DD + kc * 8;
            int dst = r * 64 + ((kc ^ (r & 7)) << 3);
            *(ushort4*)&Bh[dst] = *(const ushort4*)(hi + g);
            *(ushort4*)&Bh[dst + 4] = *(const ushort4*)(hi + g + 4);
        }
        __syncthreads();

        // B fragments: col = ni*16 + lr, k = ks*32 + lg*8
        h16x8 Fh[4][2];
        #pragma unroll
        for (int ni = 0; ni < 4; ++ni) {
            int rB = ni * 16 + lr;
            #pragma unroll
            for (int ks = 0; ks < 2; ++ks) {
                int kc  = ks * 4 + lg;
                int off = rB * 64 + ((kc ^ (rB & 7)) << 3);
                Fh[ni][ks] = *(const h16x8*)&Bh[off];
            }
        }

        // MFMA: acc = hi_a.hi_b + lo_a.hi_b  (fp32-class cosine)
        f32x4 acc[2][4];
        #pragma unroll
        for (int mi = 0; mi < 2; ++mi)
            #pragma unroll
            for (int ni = 0; ni < 4; ++ni) {
                f32x4 a = {0.f, 0.f, 0.f, 0.f};
                a = __builtin_amdgcn_mfma_f32_16x16x32_f16(Ah[mi][0], Fh[ni][0], a, 0, 0, 0);
                a = __builtin_amdgcn_mfma_f32_16x16x32_f16(Ah[mi][1], Fh[ni][1], a, 0, 0, 0);
                a = __builtin_amdgcn_mfma_f32_16x16x32_f16(Al[mi][0], Fh[ni][0], a, 0, 0, 0);
                a = __builtin_amdgcn_mfma_f32_16x16x32_f16(Al[mi][1], Fh[ni][1], a, 0, 0, 0);
                acc[mi][ni] = a;
            }

        // per-col consts
        float tt[4], qq[4];
        #pragma unroll
        for (int ni = 0; ni < 4; ++ni) {
            tt[ni] = ticrow[t0 + ni * 16 + lr];
            qq[ni] = (-C2 * tt[ni]) * tt[ni];
        }

        // fused KL epilogue (base-2)
        #pragma unroll
        for (int mi = 0; mi < 2; ++mi)
            #pragma unroll
            for (int ni = 0; ni < 4; ++ni)
                #pragma unroll
                for (int r = 0; r < 4; ++r) {
                    float arg = fmaf(b_[mi][r], tt[ni], a_[mi][r]) + qq[ni];
                    float e   = fexp2(arg);
                    float x   = fmaf(acc[mi][ni][r], si_[mi][r], sip_[mi][r]);
                    float l2  = flog2(x);
                    SP[mi][r] += e;
                    KA[mi][r] = fmaf(e, arg - l2, KA[mi][r]);
                }
    }

    // --- reduce over 16 col-lanes per k-group, write partials ---
    #pragma unroll
    for (int mi = 0; mi < 2; ++mi)
        #pragma unroll
        for (int rr = 0; rr < 4; ++rr) {
            #pragma unroll
            for (int off = 1; off < 16; off <<= 1) {
                SP[mi][rr] += __shfl_xor(SP[mi][rr], off);
                KA[mi][rr] += __shfl_xor(KA[mi][rr], off);
            }
        }
    if (lr == 0) {
        #pragma unroll
        for (int mi = 0; mi < 2; ++mi)
            #pragma unroll
            for (int rr = 0; rr < 4; ++rr) {
                int p = p0 + w * 32 + mi * 16 + lg * 4 + rr;
                part[(size_t)chunk * (BB * TT) + b * TT + p] =
                    make_float2(SP[mi][rr], KA[mi][rr]);
            }
    }
}

// ---------- kernel 3: combine partials, nonlinear reduce ----------
__global__ void k_fin(const float2* __restrict__ part, float* __restrict__ out) {
    int g = blockIdx.x * 256 + threadIdx.x;   // b*TT + p
    float SP = 0.f, KA2 = 0.f;
    #pragma unroll
    for (int c = 0; c < NCHUNK; ++c) {
        float2 q = part[(size_t)c * (BB * TT) + g];
        SP += q.x; KA2 += q.y;
    }
    float R = LN2 * (KA2 / SP) - __logf(SP);
    #pragma unroll
    for (int off = 32; off; off >>= 1) R += __shfl_xor(R, off);
    __shared__ float rb[4];
    if ((threadIdx.x & 63) == 0) rb[threadIdx.x >> 6] = R;
    __syncthreads();
    if (threadIdx.x == 0)
        atomicAdd(out, (rb[0] + rb[1] + rb[2] + rb[3]) * (1.0f / 65536.0f));
}

extern "C" void kernel_launch(void* const* d_in, const int* in_sizes, int n_in,
                              void* d_out, int out_size, void* d_ws, size_t ws_size,
                              hipStream_t stream) {
    const float* emb = (const float*)d_in[0];  // [B, T, D] fp32
    const float* tic = (const float*)d_in[1];  // [B, T] fp32
    float* out = (float*)d_out;
    char*  ws  = (char*)d_ws;

    float*          M    = (float*)(ws + OFF_M);
    unsigned short* hi   = (unsigned short*)(ws + OFF_HI);
    unsigned short* lo   = (unsigned short*)(ws + OFF_LO);
    float2*         part = (float2*)(ws + OFF_PART);

    hipMemsetAsync(out, 0, sizeof(float), stream);
    hipMemsetAsync(M, 0, BB * DD * sizeof(float), stream);

    k_prep<<<BB * 16, 256, 0, stream>>>(emb, hi, lo, M);
    k_main<<<dim3(NCHUNK * (TT / 256), BB), 512, 0, stream>>>(hi, lo, tic, M, part);
    k_fin <<<(BB * TT) / 256, 256, 0, stream>>>(part, out);
}

// Round 6
// 155.325 us; speedup vs baseline: 2.7510x; 2.7510x over previous
//
#include <hip/hip_runtime.h>
#include <hip/hip_bf16.h>
#include <math.h>

// Problem constants
#define BB 32
#define TT 2048
#define DD 64
#define NCHUNK 4
#define TCH (TT / NCHUNK)           // t-range per block (512)
#define LOG2E 1.4426950408889634f
#define C2    0.7213475204444817f   // log2(e)/2
#define LN2   0.6931471805599453f

typedef __attribute__((ext_vector_type(8))) _Float16 h16x8;  // 8 f16 (4 VGPRs)
typedef __attribute__((ext_vector_type(4))) float    f32x4;  // MFMA C/D frag

// ws layout (bytes)
#define OFF_M    0u                         // float[32*64]          = 8 KB
#define OFF_HI   8192u                      // f16[32*2048*64]       = 8 MB
#define OFF_LO   (8192u + 8388608u)         // f16[32*2048*64]       = 8 MB
#define OFF_PART (8192u + 16777216u)        // float2[NCHUNK*65536]  = 2 MB
// total ~18.8 MB

__device__ __forceinline__ float h2f(unsigned short u) {
    _Float16 h; __builtin_memcpy(&h, &u, 2); return (float)h;
}
__device__ __forceinline__ unsigned short f2h(float f) {
    _Float16 h = (_Float16)f; unsigned short u; __builtin_memcpy(&u, &h, 2); return u;
}
__device__ __forceinline__ float fexp2(float x) {
    float r; asm("v_exp_f32 %0, %1" : "=v"(r) : "v"(x)); return r;
}
__device__ __forceinline__ float flog2(float x) {
    float r; asm("v_log_f32 %0, %1" : "=v"(r) : "v"(x)); return r;
}

// ---------- kernel 1: fused L2-normalize -> f16 hi/lo split + M[b,d] sum ----------
__global__ void k_prep(const float* __restrict__ emb,
                       unsigned short* __restrict__ hi, unsigned short* __restrict__ lo,
                       float* __restrict__ M) {
    const int b    = blockIdx.x >> 4;
    const int R0   = (blockIdx.x & 15) * 128;
    const int w    = threadIdx.x >> 6;
    const int l    = threadIdx.x & 63;
    const int sub  = l >> 4;
    const int d4   = l & 15;

    float macc[4] = {0.f, 0.f, 0.f, 0.f};

    #pragma unroll
    for (int it = 0; it < 8; ++it) {
        int row = R0 + w * 32 + it * 4 + sub;
        size_t base = ((size_t)(b * TT + row)) * DD + d4 * 4;
        float4 v = *(const float4*)(emb + base);
        float ss = v.x * v.x + v.y * v.y + v.z * v.z + v.w * v.w;
        #pragma unroll
        for (int off = 1; off < 16; off <<= 1) ss += __shfl_xor(ss, off);
        float inv = 1.0f / fmaxf(sqrtf(ss), 1e-8f);
        float n0 = v.x * inv, n1 = v.y * inv, n2 = v.z * inv, n3 = v.w * inv;
        ushort4 hv, lv;
        hv.x = f2h(n0); lv.x = f2h(n0 - h2f(hv.x));
        hv.y = f2h(n1); lv.y = f2h(n1 - h2f(hv.y));
        hv.z = f2h(n2); lv.z = f2h(n2 - h2f(hv.z));
        hv.w = f2h(n3); lv.w = f2h(n3 - h2f(hv.w));
        *(ushort4*)(hi + base) = hv;
        *(ushort4*)(lo + base) = lv;
        macc[0] += n0; macc[1] += n1; macc[2] += n2; macc[3] += n3;
    }
    #pragma unroll
    for (int j = 0; j < 4; ++j) {
        macc[j] += __shfl_xor(macc[j], 16);
        macc[j] += __shfl_xor(macc[j], 32);
    }
    if (l < 16) {
        #pragma unroll
        for (int j = 0; j < 4; ++j)
            atomicAdd(&M[b * DD + d4 * 4 + j], macc[j]);
    }
}

// ---------- kernel 2: MFMA GEMM (f16 hi*hi + lo*hi) + fused KL epilogue ----------
// grid (32, 32): x = px*NCHUNK + chunk. 512 thr = 8 waves; wave owns 32 p-rows.
// launch_bounds(512,4): round-4-proven no-spill codegen (VGPR=64). VGPR=64 still
// permits 8 waves/SIMD at runtime; (512,8) forced VGPR=32 and spilled (round 5).
__launch_bounds__(512, 4)
__global__ void k_main(const unsigned short* __restrict__ hi,
                       const unsigned short* __restrict__ lo,
                       const float* __restrict__ tic,
                       const float* __restrict__ M,
                       float2* __restrict__ part) {
    __shared__ unsigned short Bh[64 * 64];   // 8 KB, swizzled [t][d]
    __shared__ float ticrow[TT];             // 8 KB
    __shared__ float Msh[DD];
    __shared__ float wred[8];

    const int b     = blockIdx.y;
    const int px    = blockIdx.x >> 2;
    const int chunk = blockIdx.x & 3;
    const int p0    = px * 256;
    const int tbase = chunk * TCH;
    const int tid   = threadIdx.x;
    const int w     = tid >> 6;
    const int l     = tid & 63;
    const int lr    = l & 15;
    const int lg    = l >> 4;

    // --- tic row: load + per-b max + normalize in LDS ---
    float m = -1e30f;
    for (int t = tid; t < TT; t += 512) {
        float v = tic[b * TT + t];
        ticrow[t] = v;
        m = fmaxf(m, v);
    }
    #pragma unroll
    for (int off = 32; off; off >>= 1) m = fmaxf(m, __shfl_xor(m, off));
    if (l == 0) wred[w] = m;
    if (tid < DD) Msh[tid] = M[b * DD + tid];
    __syncthreads();
    float mm = wred[0];
    #pragma unroll
    for (int i = 1; i < 8; ++i) mm = fmaxf(mm, wred[i]);
    float inv = 1.0f / mm;
    for (int t = tid; t < TT; t += 512) ticrow[t] *= inv;  // own entries only

    // --- persistent A fragments ---
    h16x8 Ah[2][2], Al[2][2];
    #pragma unroll
    for (int mi = 0; mi < 2; ++mi)
        #pragma unroll
        for (int ks = 0; ks < 2; ++ks) {
            size_t off = ((size_t)(b * TT + p0 + w * 32 + mi * 16 + lr)) * DD + ks * 32 + lg * 8;
            Ah[mi][ks] = *(const h16x8*)(hi + off);
            Al[mi][ks] = *(const h16x8*)(lo + off);
        }

    __syncthreads();   // normalized ticrow + Msh visible

    // --- sinv: dot(ne_p, M) from A-frags ---
    float mv[16];
    *(float4*)&mv[0]  = *(const float4*)&Msh[lg * 8];
    *(float4*)&mv[4]  = *(const float4*)&Msh[lg * 8 + 4];
    *(float4*)&mv[8]  = *(const float4*)&Msh[32 + lg * 8];
    *(float4*)&mv[12] = *(const float4*)&Msh[32 + lg * 8 + 4];
    float dotv[2];
    #pragma unroll
    for (int mi = 0; mi < 2; ++mi) {
        float s = 0.f;
        #pragma unroll
        for (int ks = 0; ks < 2; ++ks)
            #pragma unroll
            for (int e = 0; e < 8; ++e) {
                float av = (float)Ah[mi][ks][e] + (float)Al[mi][ks][e];
                s = fmaf(av, mv[ks * 8 + e], s);
            }
        s += __shfl_xor(s, 16);
        s += __shfl_xor(s, 32);
        dotv[mi] = s;
    }

    // --- per-row constants ---
    float a_[2][4], b_[2][4], si_[2][4], sip_[2][4], SP[2][4], KA[2][4];
    #pragma unroll
    for (int mi = 0; mi < 2; ++mi)
        #pragma unroll
        for (int rr = 0; rr < 4; ++rr) {
            float dv = __shfl(dotv[mi], lg * 4 + rr);
            float si = 1.0f / (dv + (float)TT);
            si_[mi][rr]  = si;
            sip_[mi][rr] = si + 1e-6f;
            float tp = ticrow[p0 + w * 32 + mi * 16 + lg * 4 + rr];
            a_[mi][rr] = -C2 * tp * tp;
            b_[mi][rr] = LOG2E * tp;
            SP[mi][rr] = 0.f; KA[mi][rr] = 0.f;
        }

    // --- t-loop over this chunk ---
    for (int tile = 0; tile < TCH / 64; ++tile) {
        const int t0 = tbase + tile * 64;
        __syncthreads();
        {   // stage B-tile (64 t x 64 d, hi only), XOR-swizzled 16B chunks
            int r  = tid >> 3;
            int kc = tid & 7;
            size_t g = ((size_t)(b * TT + t0 + r)) * DD + kc * 8;
            int dst = r * 64 + ((kc ^ (r & 7)) << 3);
            *(ushort4*)&Bh[dst] = *(const ushort4*)(hi + g);
            *(ushort4*)&Bh[dst + 4] = *(const ushort4*)(hi + g + 4);
        }
        __syncthreads();

        // B fragments
        h16x8 Fh[4][2];
        #pragma unroll
        for (int ni = 0; ni < 4; ++ni) {
            int rB = ni * 16 + lr;
            #pragma unroll
            for (int ks = 0; ks < 2; ++ks) {
                int kc  = ks * 4 + lg;
                int off = rB * 64 + ((kc ^ (rB & 7)) << 3);
                Fh[ni][ks] = *(const h16x8*)&Bh[off];
            }
        }

        // MFMA: acc = hi_a.hi_b + lo_a.hi_b
        f32x4 acc[2][4];
        #pragma unroll
        for (int mi = 0; mi < 2; ++mi)
            #pragma unroll
            for (int ni = 0; ni < 4; ++ni) {
                f32x4 a = {0.f, 0.f, 0.f, 0.f};
                a = __builtin_amdgcn_mfma_f32_16x16x32_f16(Ah[mi][0], Fh[ni][0], a, 0, 0, 0);
                a = __builtin_amdgcn_mfma_f32_16x16x32_f16(Ah[mi][1], Fh[ni][1], a, 0, 0, 0);
                a = __builtin_amdgcn_mfma_f32_16x16x32_f16(Al[mi][0], Fh[ni][0], a, 0, 0, 0);
                a = __builtin_amdgcn_mfma_f32_16x16x32_f16(Al[mi][1], Fh[ni][1], a, 0, 0, 0);
                acc[mi][ni] = a;
            }

        // per-col consts
        float tt[4], qq[4];
        #pragma unroll
        for (int ni = 0; ni < 4; ++ni) {
            tt[ni] = ticrow[t0 + ni * 16 + lr];
            qq[ni] = (-C2 * tt[ni]) * tt[ni];
        }

        // fused KL epilogue (base-2)
        #pragma unroll
        for (int mi = 0; mi < 2; ++mi)
            #pragma unroll
            for (int ni = 0; ni < 4; ++ni)
                #pragma unroll
                for (int r = 0; r < 4; ++r) {
                    float arg = fmaf(b_[mi][r], tt[ni], a_[mi][r]) + qq[ni];
                    float e   = fexp2(arg);
                    float x   = fmaf(acc[mi][ni][r], si_[mi][r], sip_[mi][r]);
                    float l2  = flog2(x);
                    SP[mi][r] += e;
                    KA[mi][r] = fmaf(e, arg - l2, KA[mi][r]);
                }
    }

    // --- reduce over 16 col-lanes per k-group, write partials ---
    #pragma unroll
    for (int mi = 0; mi < 2; ++mi)
        #pragma unroll
        for (int rr = 0; rr < 4; ++rr) {
            #pragma unroll
            for (int off = 1; off < 16; off <<= 1) {
                SP[mi][rr] += __shfl_xor(SP[mi][rr], off);
                KA[mi][rr] += __shfl_xor(KA[mi][rr], off);
            }
        }
    if (lr == 0) {
        #pragma unroll
        for (int mi = 0; mi < 2; ++mi)
            #pragma unroll
            for (int rr = 0; rr < 4; ++rr) {
                int p = p0 + w * 32 + mi * 16 + lg * 4 + rr;
                part[(size_t)chunk * (BB * TT) + b * TT + p] =
                    make_float2(SP[mi][rr], KA[mi][rr]);
            }
    }
}

// ---------- kernel 3: combine partials, nonlinear reduce ----------
__global__ void k_fin(const float2* __restrict__ part, float* __restrict__ out) {
    int g = blockIdx.x * 256 + threadIdx.x;   // b*TT + p
    float SP = 0.f, KA2 = 0.f;
    #pragma unroll
    for (int c = 0; c < NCHUNK; ++c) {
        float2 q = part[(size_t)c * (BB * TT) + g];
        SP += q.x; KA2 += q.y;
    }
    float R = LN2 * (KA2 / SP) - __logf(SP);
    #pragma unroll
    for (int off = 32; off; off >>= 1) R += __shfl_xor(R, off);
    __shared__ float rb[4];
    if ((threadIdx.x & 63) == 0) rb[threadIdx.x >> 6] = R;
    __syncthreads();
    if (threadIdx.x == 0)
        atomicAdd(out, (rb[0] + rb[1] + rb[2] + rb[3]) * (1.0f / 65536.0f));
}

extern "C" void kernel_launch(void* const* d_in, const int* in_sizes, int n_in,
                              void* d_out, int out_size, void* d_ws, size_t ws_size,
                              hipStream_t stream) {
    const float* emb = (const float*)d_in[0];  // [B, T, D] fp32
    const float* tic = (const float*)d_in[1];  // [B, T] fp32
    float* out = (float*)d_out;
    char*  ws  = (char*)d_ws;

    float*          M    = (float*)(ws + OFF_M);
    unsigned short* hi   = (unsigned short*)(ws + OFF_HI);
    unsigned short* lo   = (unsigned short*)(ws + OFF_LO);
    float2*         part = (float2*)(ws + OFF_PART);

    hipMemsetAsync(out, 0, sizeof(float), stream);
    hipMemsetAsync(M, 0, BB * DD * sizeof(float), stream);

    k_prep<<<BB * 16, 256, 0, stream>>>(emb, hi, lo, M);
    k_main<<<dim3(NCHUNK * (TT / 256), BB), 512, 0, stream>>>(hi, lo, tic, M, part);
    k_fin <<<(BB * TT) / 256, 256, 0, stream>>>(part, out);
}